// Round 2
// 1186.736 us; speedup vs baseline: 1.0921x; 1.0921x over previous
//
#include <hip/hip_runtime.h>

typedef unsigned short u16;
typedef __bf16 bf16x8 __attribute__((ext_vector_type(8)));
typedef float f32x4 __attribute__((ext_vector_type(4)));

#define N_NODES 50000
#define N_EDGES 300000
#define NP      12800000   // N_NODES*256
#define NE8     400000     // N_NODES*8

// ---------------- workspace layout (bytes), total ~122.9 MB ----------------
#define WP_OFF    0L            // packed weights bf16: 4 mats * 65536 * 2B = 524288
#define ATTN_OFF  524288L       // 4*512 f32 = 8192
#define ALPHA_OFF 532480L       // 2 f32 (+pad to 64)
#define P_OFF     532544L       // 4*NP bf16 = 102400000
#define EL_OFF    102932544L    // 4*NE8 f32 = 6400000
#define ER_OFF    109332544L    // 6400000
#define CNT_OFF   115732544L    // 4*N int = 800000
#define CUR_OFF   116532544L    // 800000
#define ROW_OFF   117332544L    // 4*(N+1) int = 800016
#define BS_OFF    118132560L    // 4*196 int = 3136
#define COL_OFF   118135696L    // 4*E int = 4800000  -> end 122935696

__device__ __forceinline__ float bf2f(u16 u){
  union { unsigned int i; float f; } v; v.i = ((unsigned int)u) << 16; return v.f;
}
__device__ __forceinline__ u16 f2bf(float f){
  union { float f; unsigned int i; } v; v.f = f;
  unsigned int x = v.i;
  x += 0x7fffu + ((x >> 16) & 1u);   // round-to-nearest-even
  return (u16)(x >> 16);
}
__device__ __forceinline__ float leaky(float x){ return x >= 0.f ? x : 0.2f * x; }

// ---------------- small setup: attn vectors, rel_out, alphas (all fp32) ----------------
__global__ void small_k(const float* __restrict__ rel_feats, const float* __restrict__ Wr,
                        const float* __restrict__ Wupd, const float* __restrict__ bupd,
                        const float* __restrict__ resw,
                        float* __restrict__ attn, float* __restrict__ alpha,
                        float* __restrict__ out_tail){
  int r = blockIdx.x, t = threadIdx.x;
  for (int j = t; j < 512; j += 256){
    float s = 0.f;
    for (int d = 0; d < 64; ++d)
      s += rel_feats[r*64 + d] * Wr[(r*64 + d)*512 + j];
    attn[r*512 + j] = s;
  }
  {
    float s = 0.f;
    for (int d = 0; d < 64; ++d)
      s += rel_feats[r*64 + d] * Wupd[(r*64 + d)*256 + t];
    out_tail[r*256 + t] = s + bupd[r*256 + t];
  }
  if (r == 0 && t < 2) alpha[t] = 1.f / (1.f + __expf(-resw[t]));
}

// ---------------- prepack fp32 weights to bf16 MFMA-B fragment layout ----------------
// Wp[m][kt][n][kk] = bf16(W[m][kt*32+kk][n]);  m: 0,1 = W_node[0..1], 2,3 = Wres[0..1]
__global__ void prepack_k(const float* __restrict__ Wn, const float* __restrict__ Wres,
                          u16* __restrict__ Wp){
  int tid = blockIdx.x*256 + threadIdx.x;          // < 262144
  int m = tid >> 16, rem = tid & 65535;
  int kt = rem >> 13, rem2 = rem & 8191;
  int n = rem2 >> 5, kk = rem2 & 31;
  const float* src = (m < 2) ? (Wn + m*65536) : (Wres + (m - 2)*65536);
  Wp[tid] = f2bf(src[(kt*32 + kk)*256 + n]);
}

// ---------------- GEMM: 256x256 bf16 weight, fp32 A, M=50000 ----------------
// Pout!=null : Pout = bf16(A@W); epilogue also emits EL/ER head-dots   (projection)
// Pout==null : out  = al*conv + (1-al)*(A@W + bias)                    (residual blend)
__global__ __launch_bounds__(256) void gemm_k(const float* __restrict__ A, const u16* __restrict__ Wp,
                                              const float* __restrict__ bias,
                                              const float* __restrict__ alpha_ws, int tix,
                                              u16* __restrict__ Pout, float* __restrict__ out,
                                              const float* __restrict__ attnL, const float* __restrict__ attnR,
                                              float* __restrict__ ELb, float* __restrict__ ERb){
  __shared__ __align__(16) u16 Bt[256*40];   // 32-k slice, padded 32->40 (2-way bank = free)
  const int tid = threadIdx.x;
  const int lane = tid & 63, wave = tid >> 6;
  const int quad = lane >> 4, n0 = lane & 15;
  const int wrow = blockIdx.x*64 + wave*16;
  const int ar = wrow + n0;
  f32x4 acc[16];
#pragma unroll
  for (int i = 0; i < 16; ++i) acc[i] = f32x4{0.f, 0.f, 0.f, 0.f};

  for (int kt = 0; kt < 8; ++kt){
    __syncthreads();
#pragma unroll
    for (int c = 0; c < 4; ++c){
      int ci = tid + c*256;
      int n = ci >> 2, g = ci & 3;
      *(uint4*)(Bt + n*40 + g*8) = *(const uint4*)(Wp + kt*8192 + n*32 + g*8);
    }
    __syncthreads();
    union { bf16x8 v; u16 s[8]; } af;
    if (ar < N_NODES){
      const float* ap = A + (size_t)ar*256 + kt*32 + quad*8;
      f32x4 a0 = *(const f32x4*)ap;
      f32x4 a1 = *(const f32x4*)(ap + 4);
#pragma unroll
      for (int j = 0; j < 4; ++j){ af.s[j] = f2bf(a0[j]); af.s[4+j] = f2bf(a1[j]); }
    } else {
#pragma unroll
      for (int j = 0; j < 8; ++j) af.s[j] = 0;
    }
#pragma unroll
    for (int nt = 0; nt < 16; ++nt){
      bf16x8 bfr = *(const bf16x8*)(Bt + (nt*16 + n0)*40 + quad*8);
      acc[nt] = __builtin_amdgcn_mfma_f32_16x16x32_bf16(af.v, bfr, acc[nt], 0, 0, 0);
    }
  }
  const bool blend = (Pout == nullptr);
  if (blend){
    float al = alpha_ws[tix];
#pragma unroll
    for (int nt = 0; nt < 16; ++nt){
      int col = nt*16 + n0;
      float b = bias[col];
#pragma unroll
      for (int reg = 0; reg < 4; ++reg){
        int row = wrow + quad*4 + reg;
        if (row < N_NODES){
          size_t ix = (size_t)row*256 + col;
          out[ix] = al * out[ix] + (1.f - al) * (acc[nt][reg] + b);
        }
      }
    }
  } else {
#pragma unroll
    for (int nt = 0; nt < 16; ++nt){
      int col = nt*16 + n0;
#pragma unroll
      for (int reg = 0; reg < 4; ++reg){
        int row = wrow + quad*4 + reg;
        if (row < N_NODES)
          Pout[(size_t)row*256 + col] = f2bf(acc[nt][reg]);
      }
    }
    // ---- fused EL/ER: per-head 32-wide dots straight from fp32 accumulators ----
    // head k covers cols [32k,32k+32) = nt 2k (d=n0) and 2k+1 (d=16+n0)
    float selL[4] = {0.f, 0.f, 0.f, 0.f};
    float selR[4] = {0.f, 0.f, 0.f, 0.f};
#pragma unroll
    for (int k = 0; k < 8; ++k){
      float a0 = attnL[k*64 + n0],      a1 = attnL[k*64 + 16 + n0];
      float b0 = attnR[k*64 + n0],      b1 = attnR[k*64 + 16 + n0];
#pragma unroll
      for (int reg = 0; reg < 4; ++reg){
        float ev = acc[2*k][reg]*a0 + acc[2*k+1][reg]*a1;
        float rv = acc[2*k][reg]*b0 + acc[2*k+1][reg]*b1;
        ev += __shfl_xor(ev, 1); ev += __shfl_xor(ev, 2);
        ev += __shfl_xor(ev, 4); ev += __shfl_xor(ev, 8);
        rv += __shfl_xor(rv, 1); rv += __shfl_xor(rv, 2);
        rv += __shfl_xor(rv, 4); rv += __shfl_xor(rv, 8);
        if (n0 == k)     selL[reg] = ev;
        if (n0 == 8 + k) selR[reg] = rv;
      }
    }
#pragma unroll
    for (int reg = 0; reg < 4; ++reg){
      int row = wrow + quad*4 + reg;
      if (row < N_NODES){
        if (n0 < 8) ELb[row*8 + n0]       = selL[reg];
        else        ERb[row*8 + (n0 - 8)] = selR[reg];
      }
    }
  }
}

// ---------------- CSR build ----------------
__global__ void zero_k(int* __restrict__ p, int n){
  int i = blockIdx.x*256 + threadIdx.x; if (i < n) p[i] = 0;
}
__global__ void hist_k(const int* __restrict__ sr, const int* __restrict__ dr,
                       const int* __restrict__ sc, const int* __restrict__ dc,
                       int* __restrict__ counts){
  int r = blockIdx.y; int e = blockIdx.x*256 + threadIdx.x;
  if (e >= N_EDGES) return;
  const int* dst = (r == 0) ? dr : (r == 1) ? sr : (r == 2) ? dc : sc;
  atomicAdd(&counts[r*N_NODES + dst[e]], 1);
}
__global__ void scan1_k(const int* __restrict__ counts, int* __restrict__ rowptr,
                        int* __restrict__ bsums){
  int r = blockIdx.y; int i = blockIdx.x*256 + threadIdx.x;
  int lane = threadIdx.x & 63, wave = threadIdx.x >> 6;
  int v = (i < N_NODES) ? counts[r*N_NODES + i] : 0;
  int orig = v;
  for (int off = 1; off < 64; off <<= 1){ int t = __shfl_up(v, off); if (lane >= off) v += t; }
  __shared__ int wsum[4];
  if (lane == 63) wsum[wave] = v;
  __syncthreads();
  int add = 0;
  for (int w = 0; w < wave; ++w) add += wsum[w];
  v += add;
  if (i < N_NODES) rowptr[r*(N_NODES+1) + i] = v - orig;   // exclusive within block
  if (threadIdx.x == 255) bsums[r*196 + blockIdx.x] = v;
}
__global__ void scan2_k(int* __restrict__ bsums){   // 1 block; wave r scans its 196 sums
  int lane = threadIdx.x & 63, r = threadIdx.x >> 6;
  int carry = 0;
  for (int c = 0; c < 4; ++c){
    int i = c*64 + lane;
    int v = (i < 196) ? bsums[r*196 + i] : 0;
    int orig = v;
    for (int off = 1; off < 64; off <<= 1){ int t = __shfl_up(v, off); if (lane >= off) v += t; }
    int excl = v - orig + carry;
    if (i < 196) bsums[r*196 + i] = excl;
    carry += __shfl(v, 63);
  }
}
__global__ void scan3_k(const int* __restrict__ bsums, int* __restrict__ rowptr){
  int r = blockIdx.y; int i = blockIdx.x*256 + threadIdx.x;
  if (i < N_NODES) rowptr[r*(N_NODES+1) + i] += bsums[r*196 + blockIdx.x];
  if (i == N_NODES) rowptr[r*(N_NODES+1) + N_NODES] = N_EDGES;
}
__global__ void scatter_k(const int* __restrict__ sr, const int* __restrict__ dr,
                          const int* __restrict__ sc, const int* __restrict__ dc,
                          const int* __restrict__ rowptr, int* __restrict__ cur,
                          int* __restrict__ colsrc){
  int r = blockIdx.y; int e = blockIdx.x*256 + threadIdx.x;
  if (e >= N_EDGES) return;
  const int* dst = (r == 0) ? dr : (r == 1) ? sr : (r == 2) ? dc : sc;
  const int* src = (r == 0) ? sr : (r == 1) ? dr : (r == 2) ? sc : dc;
  int d = dst[e];
  int pos = rowptr[r*(N_NODES+1) + d] + atomicAdd(&cur[r*N_NODES + d], 1);
  colsrc[r*N_EDGES + pos] = src[e];
}

// ---------------- per-relation GAT aggregation: writes relu(conv) fp32 to d_out ----------------
// one wave per (node, relation); lane owns 4 cols (single head k0 = lane>>3).
// single pass, shift-softmax exp(x-10) (max over x is ~14 statistically; shift cancels in a/z).
// 8 edges per chunk: cooperative colsrc load, 64-wide el gather, 8 P-row gathers in flight.
__global__ __launch_bounds__(256) void aggregate_k(
    const int* __restrict__ rowptr, const int* __restrict__ colsrc,
    const float* __restrict__ EL, const float* __restrict__ ER,
    const u16* __restrict__ P, float* __restrict__ NR){
  const int r = blockIdx.y;
  const int wave = threadIdx.x >> 6, lane = threadIdx.x & 63;
  const int n = blockIdx.x*4 + wave;
  if (n >= N_NODES) return;
  const int k0 = lane >> 3, j = lane & 7;
  const int rp0 = rowptr[r*(N_NODES+1) + n], rp1 = rowptr[r*(N_NODES+1) + n + 1];
  const float er = ER[(size_t)r*NE8 + n*8 + k0];
  const float* el = EL + (size_t)r*NE8;
  const int* cs = colsrc + r*N_EDGES;
  const u16* Ps = P + (size_t)(r ^ 1)*NP;

  float z = 0.f, a0 = 0.f, a1 = 0.f, a2 = 0.f, a3 = 0.f;
  for (int base = rp0; base < rp1; base += 8){
    const int cnt = rp1 - base;
    const int m = cnt < 8 ? cnt : 8;
    // lane (k0,j) owns edge base+j: one coalesced cs load, one 64-wide el gather
    int sj = cs[base + (j < m ? j : 0)];
    float x = leaky(el[sj*8 + k0] + er);
    float p = (j < m) ? __expf(x - 10.f) : 0.f;
    ushort4 hv[8]; float pv[8];
#pragma unroll
    for (int t = 0; t < 8; ++t){
      if (t < m){
        int s = __shfl(sj, t);                                   // uniform broadcast
        hv[t] = *(const ushort4*)(Ps + (size_t)s*256 + lane*4);  // 512B coalesced row
        pv[t] = __shfl(p, (lane & 56) | t);                      // p(edge t, head k0)
      }
    }
#pragma unroll
    for (int t = 0; t < 8; ++t){
      if (t < m){
        float q = pv[t];
        z += q;
        a0 += q*bf2f(hv[t].x); a1 += q*bf2f(hv[t].y);
        a2 += q*bf2f(hv[t].z); a3 += q*bf2f(hv[t].w);
      }
    }
  }
  float inv = (rp1 > rp0) ? 1.f / z : 0.f;
  f32x4 o;
  o[0] = fmaxf(a0*inv, 0.f);
  o[1] = fmaxf(a1*inv, 0.f);
  o[2] = fmaxf(a2*inv, 0.f);
  o[3] = fmaxf(a3*inv, 0.f);
  *(f32x4*)(NR + (size_t)r*NP + (size_t)n*256 + lane*4) = o;
}

// ---------------- cross-relation attention (groups {0,2} and {1,3}), fp32 in-place on d_out ----------------
__global__ __launch_bounds__(256) void cross_k(const float* __restrict__ rel_attn,
                                               float* __restrict__ out){
  const int g = blockIdx.y;                    // group: relations {g, g+2}
  const int wave = threadIdx.x >> 6, lane = threadIdx.x & 63;
  const int n = blockIdx.x*4 + wave;
  if (n >= N_NODES) return;
  const int k0 = lane >> 3;
  f32x4 h0 = *(const f32x4*)(out + (size_t)g*NP       + (size_t)n*256 + lane*4);
  f32x4 h1 = *(const f32x4*)(out + (size_t)(g + 2)*NP + (size_t)n*256 + lane*4);
#pragma unroll
  for (int which = 0; which < 2; ++which){
    int rr = g + which*2;
    const float* ra = rel_attn + rr*256 + k0*32 + (lane & 7)*4;
    float s0 = 0.f, s1 = 0.f;
#pragma unroll
    for (int j = 0; j < 4; ++j){
      float a = ra[j];
      s0 += a * h0[j]; s1 += a * h1[j];
    }
    s0 += __shfl_xor(s0, 1); s1 += __shfl_xor(s1, 1);
    s0 += __shfl_xor(s0, 2); s1 += __shfl_xor(s1, 2);
    s0 += __shfl_xor(s0, 4); s1 += __shfl_xor(s1, 4);
    float l0 = leaky(s0), l1 = leaky(s1);
    float mx = fmaxf(l0, l1);
    float e0 = __expf(l0 - mx), e1 = __expf(l1 - mx);
    float w0 = e0 / (e0 + e1), w1 = 1.f - w0;
    f32x4 o;
#pragma unroll
    for (int j = 0; j < 4; ++j) o[j] = w0*h0[j] + w1*h1[j];
    *(f32x4*)(out + ((size_t)rr*N_NODES + n)*256 + lane*4) = o;
  }
}

extern "C" void kernel_launch(void* const* d_in, const int* in_sizes, int n_in,
                              void* d_out, int out_size, void* d_ws, size_t ws_size,
                              hipStream_t stream) {
  (void)in_sizes; (void)n_in; (void)out_size; (void)ws_size;
  const float* feats      = (const float*)d_in[0];
  const float* rel_feats  = (const float*)d_in[1];
  const int*   src_rates  = (const int*)d_in[2];
  const int*   dst_rates  = (const int*)d_in[3];
  const int*   src_clicks = (const int*)d_in[4];
  const int*   dst_clicks = (const int*)d_in[5];
  const float* W_node     = (const float*)d_in[6];
  const float* Wr         = (const float*)d_in[7];
  const float* Wres       = (const float*)d_in[8];
  const float* bres       = (const float*)d_in[9];
  const float* resw       = (const float*)d_in[10];
  const float* rel_attn   = (const float*)d_in[11];
  const float* Wupd       = (const float*)d_in[12];
  const float* bupd       = (const float*)d_in[13];

  char* w = (char*)d_ws;
  u16*   Wp     = (u16*)(w + WP_OFF);
  float* attn   = (float*)(w + ATTN_OFF);
  float* alpha  = (float*)(w + ALPHA_OFF);
  u16*   P      = (u16*)(w + P_OFF);
  float* EL     = (float*)(w + EL_OFF);
  float* ER     = (float*)(w + ER_OFF);
  int*   counts = (int*)(w + CNT_OFF);
  int*   cur    = (int*)(w + CUR_OFF);
  int*   rowptr = (int*)(w + ROW_OFF);
  int*   bsums  = (int*)(w + BS_OFF);
  int*   colsrc = (int*)(w + COL_OFF);
  float* out    = (float*)d_out;

  static const int DT[4] = {1, 0, 1, 0};   // DTYPE per relation / feat index

  // zero counts + cursors (contiguous: 400000 ints)
  zero_k<<<1563, 256, 0, stream>>>(counts, 400000);
  small_k<<<4, 256, 0, stream>>>(rel_feats, Wr, Wupd, bupd, resw, attn, alpha,
                                 out + (size_t)4*NP);
  prepack_k<<<1024, 256, 0, stream>>>(W_node, Wres, Wp);

  hist_k<<<dim3(1172, 4), 256, 0, stream>>>(src_rates, dst_rates, src_clicks, dst_clicks, counts);
  scan1_k<<<dim3(196, 4), 256, 0, stream>>>(counts, rowptr, bsums);
  scan2_k<<<1, 256, 0, stream>>>(bsums);
  scan3_k<<<dim3(196, 4), 256, 0, stream>>>(bsums, rowptr);
  scatter_k<<<dim3(1172, 4), 256, 0, stream>>>(src_rates, dst_rates, src_clicks, dst_clicks,
                                               rowptr, cur, colsrc);

  // projections P[i] = bf16(feats[i] @ W_node[DT[i]]), fused EL[i^1]/ER[i] epilogue
  for (int i = 0; i < 4; ++i)
    gemm_k<<<782, 256, 0, stream>>>(feats + (size_t)i*NP, Wp + DT[i]*65536, nullptr,
                                    alpha, 0, P + (size_t)i*NP, nullptr,
                                    attn + (i ^ 1)*512, attn + i*512 + 32,
                                    EL + (size_t)(i ^ 1)*NE8, ER + (size_t)i*NE8);

  // conv (pre-residual, relu'd) -> d_out fp32
  aggregate_k<<<dim3(12500, 4), 256, 0, stream>>>(rowptr, colsrc, EL, ER, P, out);
  // residual blend in-place: out = al*conv + (1-al)*(feats@Wres + bres)
  for (int r = 0; r < 4; ++r)
    gemm_k<<<782, 256, 0, stream>>>(feats + (size_t)r*NP, Wp + (2 + DT[r])*65536,
                                    bres + DT[r]*256, alpha, DT[r],
                                    nullptr, out + (size_t)r*NP,
                                    nullptr, nullptr, nullptr, nullptr);

  cross_k<<<dim3(12500, 2), 256, 0, stream>>>(rel_attn, out);
}

// Round 3
// 1032.929 us; speedup vs baseline: 1.2547x; 1.1489x over previous
//
#include <hip/hip_runtime.h>

typedef unsigned short u16;
typedef __bf16 bf16x8 __attribute__((ext_vector_type(8)));
typedef float f32x4 __attribute__((ext_vector_type(4)));

#define N_NODES 50000
#define N_EDGES 300000
#define NP      12800000   // N_NODES*256
#define NE8     400000     // N_NODES*8

// ---------------- workspace layout (bytes), total ~122.9 MB ----------------
#define WP_OFF    0L            // packed weights bf16: 4 mats * 65536 * 2B = 524288
#define ATTN_OFF  524288L       // 4*512 f32 = 8192
#define ALPHA_OFF 532480L       // 2 f32 (+pad to 64)
#define P_OFF     532544L       // 4*NP bf16 = 102400000
#define EL_OFF    102932544L    // 4*NE8 f32 = 6400000
#define ER_OFF    109332544L    // 6400000
#define CNT_OFF   115732544L    // 4*N int = 800000
#define CUR_OFF   116532544L    // 800000
#define ROW_OFF   117332544L    // 4*(N+1) int = 800016
#define BS_OFF    118132560L    // 4*196 int = 3136
#define COL_OFF   118135696L    // 4*E int = 4800000  -> end 122935696

__device__ __forceinline__ float bf2f(u16 u){
  union { unsigned int i; float f; } v; v.i = ((unsigned int)u) << 16; return v.f;
}
__device__ __forceinline__ u16 f2bf(float f){
  union { float f; unsigned int i; } v; v.f = f;
  unsigned int x = v.i;
  x += 0x7fffu + ((x >> 16) & 1u);   // round-to-nearest-even
  return (u16)(x >> 16);
}
__device__ __forceinline__ float leaky(float x){ return x >= 0.f ? x : 0.2f * x; }

// ---------------- small setup: attn vectors, rel_out, alphas (all fp32) ----------------
__global__ void small_k(const float* __restrict__ rel_feats, const float* __restrict__ Wr,
                        const float* __restrict__ Wupd, const float* __restrict__ bupd,
                        const float* __restrict__ resw,
                        float* __restrict__ attn, float* __restrict__ alpha,
                        float* __restrict__ out_tail){
  int r = blockIdx.x, t = threadIdx.x;
  for (int j = t; j < 512; j += 256){
    float s = 0.f;
    for (int d = 0; d < 64; ++d)
      s += rel_feats[r*64 + d] * Wr[(r*64 + d)*512 + j];
    attn[r*512 + j] = s;
  }
  {
    float s = 0.f;
    for (int d = 0; d < 64; ++d)
      s += rel_feats[r*64 + d] * Wupd[(r*64 + d)*256 + t];
    out_tail[r*256 + t] = s + bupd[r*256 + t];
  }
  if (r == 0 && t < 2) alpha[t] = 1.f / (1.f + __expf(-resw[t]));
}

// ---------------- prepack fp32 weights to bf16 MFMA-B fragment layout ----------------
// Wp[m][kt][n][kk] = bf16(W[m][kt*32+kk][n]);  m: 0,1 = W_node[0..1], 2,3 = Wres[0..1]
__global__ void prepack_k(const float* __restrict__ Wn, const float* __restrict__ Wres,
                          u16* __restrict__ Wp){
  int tid = blockIdx.x*256 + threadIdx.x;          // < 262144
  int m = tid >> 16, rem = tid & 65535;
  int kt = rem >> 13, rem2 = rem & 8191;
  int n = rem2 >> 5, kk = rem2 & 31;
  const float* src = (m < 2) ? (Wn + m*65536) : (Wres + (m - 2)*65536);
  Wp[tid] = f2bf(src[(kt*32 + kk)*256 + n]);
}

// ---------------- fused dual GEMM: one pass over A, two 256x256 bf16 weights ----------------
// Writes: Pout = bf16(A@Wn)  (projection, feeds gathers)
//         out  = (1-al)*(A@Wres + bias)   (pre-scaled inherit, fp32)
//         ELb/ERb head-dots from fp32 accumulators of A@Wn
__global__ __launch_bounds__(256) void gemm_k(const float* __restrict__ A,
                                              const u16* __restrict__ Wpn, const u16* __restrict__ Wpr,
                                              const float* __restrict__ bias,
                                              const float* __restrict__ alpha_ws, int tix,
                                              u16* __restrict__ Pout, float* __restrict__ out,
                                              const float* __restrict__ attnL, const float* __restrict__ attnR,
                                              float* __restrict__ ELb, float* __restrict__ ERb){
  __shared__ __align__(16) u16 Btn[256*40];   // 32-k slice of Wn, padded 32->40
  __shared__ __align__(16) u16 Btr[256*40];   // 32-k slice of Wres
  const int tid = threadIdx.x;
  const int lane = tid & 63, wave = tid >> 6;
  const int quad = lane >> 4, n0 = lane & 15;
  const int wrow = blockIdx.x*64 + wave*16;
  const int ar = wrow + n0;
  f32x4 accn[16], accr[16];
#pragma unroll
  for (int i = 0; i < 16; ++i){ accn[i] = f32x4{0.f,0.f,0.f,0.f}; accr[i] = f32x4{0.f,0.f,0.f,0.f}; }

  for (int kt = 0; kt < 8; ++kt){
    __syncthreads();
#pragma unroll
    for (int c = 0; c < 4; ++c){
      int ci = tid + c*256;
      int nn = ci >> 2, gg = ci & 3;
      *(uint4*)(Btn + nn*40 + gg*8) = *(const uint4*)(Wpn + kt*8192 + nn*32 + gg*8);
      *(uint4*)(Btr + nn*40 + gg*8) = *(const uint4*)(Wpr + kt*8192 + nn*32 + gg*8);
    }
    __syncthreads();
    union { bf16x8 v; u16 s[8]; } af;
    if (ar < N_NODES){
      const float* ap = A + (size_t)ar*256 + kt*32 + quad*8;
      f32x4 a0 = *(const f32x4*)ap;
      f32x4 a1 = *(const f32x4*)(ap + 4);
#pragma unroll
      for (int j = 0; j < 4; ++j){ af.s[j] = f2bf(a0[j]); af.s[4+j] = f2bf(a1[j]); }
    } else {
#pragma unroll
      for (int j = 0; j < 8; ++j) af.s[j] = 0;
    }
#pragma unroll
    for (int nt = 0; nt < 16; ++nt){
      bf16x8 bn = *(const bf16x8*)(Btn + (nt*16 + n0)*40 + quad*8);
      bf16x8 br = *(const bf16x8*)(Btr + (nt*16 + n0)*40 + quad*8);
      accn[nt] = __builtin_amdgcn_mfma_f32_16x16x32_bf16(af.v, bn, accn[nt], 0, 0, 0);
      accr[nt] = __builtin_amdgcn_mfma_f32_16x16x32_bf16(af.v, br, accr[nt], 0, 0, 0);
    }
  }
  const float one_m_al = 1.f - alpha_ws[tix];
  // inherit (pre-scaled) + projection writes
#pragma unroll
  for (int nt = 0; nt < 16; ++nt){
    int col = nt*16 + n0;
    float b = bias[col];
#pragma unroll
    for (int reg = 0; reg < 4; ++reg){
      int row = wrow + quad*4 + reg;
      if (row < N_NODES){
        out[(size_t)row*256 + col] = one_m_al * (accr[nt][reg] + b);
        Pout[(size_t)row*256 + col] = f2bf(accn[nt][reg]);
      }
    }
  }
  // ---- fused EL/ER: per-head 32-wide dots straight from fp32 accumulators ----
  // head k covers cols [32k,32k+32) = nt 2k (d=n0) and 2k+1 (d=16+n0)
  float selL[4] = {0.f, 0.f, 0.f, 0.f};
  float selR[4] = {0.f, 0.f, 0.f, 0.f};
#pragma unroll
  for (int k = 0; k < 8; ++k){
    float a0 = attnL[k*64 + n0],      a1 = attnL[k*64 + 16 + n0];
    float b0 = attnR[k*64 + n0],      b1 = attnR[k*64 + 16 + n0];
#pragma unroll
    for (int reg = 0; reg < 4; ++reg){
      float ev = accn[2*k][reg]*a0 + accn[2*k+1][reg]*a1;
      float rv = accn[2*k][reg]*b0 + accn[2*k+1][reg]*b1;
      ev += __shfl_xor(ev, 1); ev += __shfl_xor(ev, 2);
      ev += __shfl_xor(ev, 4); ev += __shfl_xor(ev, 8);
      rv += __shfl_xor(rv, 1); rv += __shfl_xor(rv, 2);
      rv += __shfl_xor(rv, 4); rv += __shfl_xor(rv, 8);
      if (n0 == k)     selL[reg] = ev;
      if (n0 == 8 + k) selR[reg] = rv;
    }
  }
#pragma unroll
  for (int reg = 0; reg < 4; ++reg){
    int row = wrow + quad*4 + reg;
    if (row < N_NODES){
      if (n0 < 8) ELb[row*8 + n0]       = selL[reg];
      else        ERb[row*8 + (n0 - 8)] = selR[reg];
    }
  }
}

// ---------------- CSR build ----------------
__global__ void zero_k(int* __restrict__ p, int n){
  int i = blockIdx.x*256 + threadIdx.x; if (i < n) p[i] = 0;
}
__global__ void hist_k(const int* __restrict__ sr, const int* __restrict__ dr,
                       const int* __restrict__ sc, const int* __restrict__ dc,
                       int* __restrict__ counts){
  int r = blockIdx.y; int e = blockIdx.x*256 + threadIdx.x;
  if (e >= N_EDGES) return;
  const int* dst = (r == 0) ? dr : (r == 1) ? sr : (r == 2) ? dc : sc;
  atomicAdd(&counts[r*N_NODES + dst[e]], 1);
}
__global__ void scan1_k(const int* __restrict__ counts, int* __restrict__ rowptr,
                        int* __restrict__ bsums){
  int r = blockIdx.y; int i = blockIdx.x*256 + threadIdx.x;
  int lane = threadIdx.x & 63, wave = threadIdx.x >> 6;
  int v = (i < N_NODES) ? counts[r*N_NODES + i] : 0;
  int orig = v;
  for (int off = 1; off < 64; off <<= 1){ int t = __shfl_up(v, off); if (lane >= off) v += t; }
  __shared__ int wsum[4];
  if (lane == 63) wsum[wave] = v;
  __syncthreads();
  int add = 0;
  for (int w = 0; w < wave; ++w) add += wsum[w];
  v += add;
  if (i < N_NODES) rowptr[r*(N_NODES+1) + i] = v - orig;   // exclusive within block
  if (threadIdx.x == 255) bsums[r*196 + blockIdx.x] = v;
}
__global__ void scan2_k(int* __restrict__ bsums){   // 1 block; wave r scans its 196 sums
  int lane = threadIdx.x & 63, r = threadIdx.x >> 6;
  int carry = 0;
  for (int c = 0; c < 4; ++c){
    int i = c*64 + lane;
    int v = (i < 196) ? bsums[r*196 + i] : 0;
    int orig = v;
    for (int off = 1; off < 64; off <<= 1){ int t = __shfl_up(v, off); if (lane >= off) v += t; }
    int excl = v - orig + carry;
    if (i < 196) bsums[r*196 + i] = excl;
    carry += __shfl(v, 63);
  }
}
__global__ void scan3_k(const int* __restrict__ bsums, int* __restrict__ rowptr){
  int r = blockIdx.y; int i = blockIdx.x*256 + threadIdx.x;
  if (i < N_NODES) rowptr[r*(N_NODES+1) + i] += bsums[r*196 + blockIdx.x];
  if (i == N_NODES) rowptr[r*(N_NODES+1) + N_NODES] = N_EDGES;
}
__global__ void scatter_k(const int* __restrict__ sr, const int* __restrict__ dr,
                          const int* __restrict__ sc, const int* __restrict__ dc,
                          const int* __restrict__ rowptr, int* __restrict__ cur,
                          int* __restrict__ colsrc){
  int r = blockIdx.y; int e = blockIdx.x*256 + threadIdx.x;
  if (e >= N_EDGES) return;
  const int* dst = (r == 0) ? dr : (r == 1) ? sr : (r == 2) ? dc : sc;
  const int* src = (r == 0) ? sr : (r == 1) ? dr : (r == 2) ? sc : dc;
  int d = dst[e];
  int pos = rowptr[r*(N_NODES+1) + d] + atomicAdd(&cur[r*N_NODES + d], 1);
  colsrc[r*N_EDGES + pos] = src[e];
}

// ---------------- fused aggregate + residual blend + cross-relation attention ----------------
// one wave per (node, group g); handles relations {g, g+2} (same dtype -> same alpha).
// conv: single pass shift-softmax exp(x-10), 8-deep gather pipeline (as round-2 aggregate_k).
// blend: h = al*relu(conv) + inherit (inherit pre-scaled by (1-al), read from out).
// cross: 2-way softmax over the group in registers, final write to out.
__global__ __launch_bounds__(256) void aggcross_k(
    const int* __restrict__ rowptr, const int* __restrict__ colsrc,
    const float* __restrict__ EL, const float* __restrict__ ER,
    const u16* __restrict__ P, const float* __restrict__ rel_attn,
    const float* __restrict__ alpha_ws, float* __restrict__ out){
  const int g = blockIdx.y;                    // group base relation: {g, g+2}
  const int wave = threadIdx.x >> 6, lane = threadIdx.x & 63;
  const int n = blockIdx.x*4 + wave;
  if (n >= N_NODES) return;
  const int k0 = lane >> 3, j = lane & 7;
  const float al = alpha_ws[g ^ 1];            // DTYPE[g]: g=0 -> 1, g=1 -> 0
  f32x4 h[2];
#pragma unroll
  for (int which = 0; which < 2; ++which){
    const int r = g + which*2;
    const int rp0 = rowptr[r*(N_NODES+1) + n], rp1 = rowptr[r*(N_NODES+1) + n + 1];
    const float er = ER[(size_t)r*NE8 + n*8 + k0];
    const float* el = EL + (size_t)r*NE8;
    const int* cs = colsrc + r*N_EDGES;
    const u16* Ps = P + (size_t)(r ^ 1)*NP;

    float z = 0.f, a0 = 0.f, a1 = 0.f, a2 = 0.f, a3 = 0.f;
    for (int base = rp0; base < rp1; base += 8){
      const int cnt = rp1 - base;
      const int m = cnt < 8 ? cnt : 8;
      int sj = cs[base + (j < m ? j : 0)];
      float x = leaky(el[sj*8 + k0] + er);
      float p = (j < m) ? __expf(x - 10.f) : 0.f;
      ushort4 hv[8]; float pv[8];
#pragma unroll
      for (int t = 0; t < 8; ++t){
        if (t < m){
          int s = __shfl(sj, t);                                   // uniform broadcast
          hv[t] = *(const ushort4*)(Ps + (size_t)s*256 + lane*4);  // 512B coalesced row
          pv[t] = __shfl(p, (lane & 56) | t);                      // p(edge t, head k0)
        }
      }
#pragma unroll
      for (int t = 0; t < 8; ++t){
        if (t < m){
          float q = pv[t];
          z += q;
          a0 += q*bf2f(hv[t].x); a1 += q*bf2f(hv[t].y);
          a2 += q*bf2f(hv[t].z); a3 += q*bf2f(hv[t].w);
        }
      }
    }
    float inv = (rp1 > rp0) ? 1.f / z : 0.f;
    f32x4 inh = *(const f32x4*)(out + (size_t)r*NP + (size_t)n*256 + lane*4);
    h[which][0] = al * fmaxf(a0*inv, 0.f) + inh[0];
    h[which][1] = al * fmaxf(a1*inv, 0.f) + inh[1];
    h[which][2] = al * fmaxf(a2*inv, 0.f) + inh[2];
    h[which][3] = al * fmaxf(a3*inv, 0.f) + inh[3];
  }
  // cross-relation attention over {h[0], h[1]}
#pragma unroll
  for (int which = 0; which < 2; ++which){
    int rr = g + which*2;
    const float* ra = rel_attn + rr*256 + k0*32 + j*4;
    float s0 = 0.f, s1 = 0.f;
#pragma unroll
    for (int jj = 0; jj < 4; ++jj){
      float a = ra[jj];
      s0 += a * h[0][jj]; s1 += a * h[1][jj];
    }
    s0 += __shfl_xor(s0, 1); s1 += __shfl_xor(s1, 1);
    s0 += __shfl_xor(s0, 2); s1 += __shfl_xor(s1, 2);
    s0 += __shfl_xor(s0, 4); s1 += __shfl_xor(s1, 4);
    float l0 = leaky(s0), l1 = leaky(s1);
    float mx = fmaxf(l0, l1);
    float e0 = __expf(l0 - mx), e1 = __expf(l1 - mx);
    float w0 = e0 / (e0 + e1), w1 = 1.f - w0;
    f32x4 o;
#pragma unroll
    for (int jj = 0; jj < 4; ++jj) o[jj] = w0*h[0][jj] + w1*h[1][jj];
    *(f32x4*)(out + ((size_t)rr*N_NODES + n)*256 + lane*4) = o;
  }
}

extern "C" void kernel_launch(void* const* d_in, const int* in_sizes, int n_in,
                              void* d_out, int out_size, void* d_ws, size_t ws_size,
                              hipStream_t stream) {
  (void)in_sizes; (void)n_in; (void)out_size; (void)ws_size;
  const float* feats      = (const float*)d_in[0];
  const float* rel_feats  = (const float*)d_in[1];
  const int*   src_rates  = (const int*)d_in[2];
  const int*   dst_rates  = (const int*)d_in[3];
  const int*   src_clicks = (const int*)d_in[4];
  const int*   dst_clicks = (const int*)d_in[5];
  const float* W_node     = (const float*)d_in[6];
  const float* Wr         = (const float*)d_in[7];
  const float* Wres       = (const float*)d_in[8];
  const float* bres       = (const float*)d_in[9];
  const float* resw       = (const float*)d_in[10];
  const float* rel_attn   = (const float*)d_in[11];
  const float* Wupd       = (const float*)d_in[12];
  const float* bupd       = (const float*)d_in[13];

  char* w = (char*)d_ws;
  u16*   Wp     = (u16*)(w + WP_OFF);
  float* attn   = (float*)(w + ATTN_OFF);
  float* alpha  = (float*)(w + ALPHA_OFF);
  u16*   P      = (u16*)(w + P_OFF);
  float* EL     = (float*)(w + EL_OFF);
  float* ER     = (float*)(w + ER_OFF);
  int*   counts = (int*)(w + CNT_OFF);
  int*   cur    = (int*)(w + CUR_OFF);
  int*   rowptr = (int*)(w + ROW_OFF);
  int*   bsums  = (int*)(w + BS_OFF);
  int*   colsrc = (int*)(w + COL_OFF);
  float* out    = (float*)d_out;

  static const int DT[4] = {1, 0, 1, 0};   // DTYPE per relation / feat index

  // zero counts + cursors (contiguous: 400000 ints)
  zero_k<<<1563, 256, 0, stream>>>(counts, 400000);
  small_k<<<4, 256, 0, stream>>>(rel_feats, Wr, Wupd, bupd, resw, attn, alpha,
                                 out + (size_t)4*NP);
  prepack_k<<<1024, 256, 0, stream>>>(W_node, Wres, Wp);

  hist_k<<<dim3(1172, 4), 256, 0, stream>>>(src_rates, dst_rates, src_clicks, dst_clicks, counts);
  scan1_k<<<dim3(196, 4), 256, 0, stream>>>(counts, rowptr, bsums);
  scan2_k<<<1, 256, 0, stream>>>(bsums);
  scan3_k<<<dim3(196, 4), 256, 0, stream>>>(bsums, rowptr);
  scatter_k<<<dim3(1172, 4), 256, 0, stream>>>(src_rates, dst_rates, src_clicks, dst_clicks,
                                               rowptr, cur, colsrc);

  // fused dual GEMM per relation: P[i]=bf16(feats@Wn), out[i]=(1-al)*(feats@Wres+b),
  // EL[i^1]/ER[i] from fp32 accumulators
  for (int i = 0; i < 4; ++i)
    gemm_k<<<782, 256, 0, stream>>>(feats + (size_t)i*NP,
                                    Wp + DT[i]*65536, Wp + (2 + DT[i])*65536,
                                    bres + DT[i]*256, alpha, DT[i],
                                    P + (size_t)i*NP, out + (size_t)i*NP,
                                    attn + (i ^ 1)*512, attn + i*512 + 32,
                                    EL + (size_t)(i ^ 1)*NE8, ER + (size_t)i*NE8);

  // fused aggregate + blend + cross: groups {0,2} and {1,3}
  aggcross_k<<<dim3(12500, 2), 256, 0, stream>>>(rowptr, colsrc, EL, ER, P,
                                                 rel_attn, alpha, out);
}

// Round 4
// 927.014 us; speedup vs baseline: 1.3981x; 1.1143x over previous
//
#include <hip/hip_runtime.h>

typedef unsigned short u16;
typedef __bf16 bf16x8 __attribute__((ext_vector_type(8)));
typedef float f32x4 __attribute__((ext_vector_type(4)));

#define N_NODES 50000
#define N_EDGES 300000
#define NP      12800000   // N_NODES*256
#define NE8     400000     // N_NODES*8

// ---------------- workspace layout (bytes), total ~122.9 MB ----------------
#define WP_OFF    0L            // packed weights bf16: 4 mats * 65536 * 2B = 524288
#define ATTN_OFF  524288L       // 4*512 f32 = 8192
#define ALPHA_OFF 532480L       // 2 f32 (+pad to 64)
#define P_OFF     532544L       // 4*NP bf16 = 102400000
#define EL_OFF    102932544L    // 4*NE8 f32 = 6400000
#define ER_OFF    109332544L    // 6400000
#define CNT_OFF   115732544L    // 4*N int = 800000
#define CUR_OFF   116532544L    // 800000
#define ROW_OFF   117332544L    // 4*(N+1) int = 800016
#define BS_OFF    118132560L    // 4*196 int = 3136
#define COL_OFF   118135696L    // 4*E int = 4800000  -> end 122935696

__device__ __forceinline__ float bf2f(u16 u){
  union { unsigned int i; float f; } v; v.i = ((unsigned int)u) << 16; return v.f;
}
__device__ __forceinline__ u16 f2bf(float f){
  union { float f; unsigned int i; } v; v.f = f;
  unsigned int x = v.i;
  x += 0x7fffu + ((x >> 16) & 1u);   // round-to-nearest-even
  return (u16)(x >> 16);
}
__device__ __forceinline__ float leaky(float x){ return x >= 0.f ? x : 0.2f * x; }

// ---------------- small setup: attn vectors, rel_out, alphas (all fp32) ----------------
__global__ void small_k(const float* __restrict__ rel_feats, const float* __restrict__ Wr,
                        const float* __restrict__ Wupd, const float* __restrict__ bupd,
                        const float* __restrict__ resw,
                        float* __restrict__ attn, float* __restrict__ alpha,
                        float* __restrict__ out_tail){
  int r = blockIdx.x, t = threadIdx.x;
  for (int j = t; j < 512; j += 256){
    float s = 0.f;
    for (int d = 0; d < 64; ++d)
      s += rel_feats[r*64 + d] * Wr[(r*64 + d)*512 + j];
    attn[r*512 + j] = s;
  }
  {
    float s = 0.f;
    for (int d = 0; d < 64; ++d)
      s += rel_feats[r*64 + d] * Wupd[(r*64 + d)*256 + t];
    out_tail[r*256 + t] = s + bupd[r*256 + t];
  }
  if (r == 0 && t < 2) alpha[t] = 1.f / (1.f + __expf(-resw[t]));
}

// ---------------- prepack fp32 weights to bf16 MFMA-B fragment layout ----------------
// Wp[m][kt][n][kk] = bf16(W[m][kt*32+kk][n]);  m: 0,1 = W_node[0..1], 2,3 = Wres[0..1]
__global__ void prepack_k(const float* __restrict__ Wn, const float* __restrict__ Wres,
                          u16* __restrict__ Wp){
  int tid = blockIdx.x*256 + threadIdx.x;          // < 262144
  int m = tid >> 16, rem = tid & 65535;
  int kt = rem >> 13, rem2 = rem & 8191;
  int n = rem2 >> 5, kk = rem2 & 31;
  const float* src = (m < 2) ? (Wn + m*65536) : (Wres + (m - 2)*65536);
  Wp[tid] = f2bf(src[(kt*32 + kk)*256 + n]);
}

// ---------------- fused dual GEMM, barrier-free / LDS-free ----------------
// Block: 64 rows x 256 cols. Wave w: 64 rows x cols [w*64, w*64+64), BOTH matrices.
// B fragments loaded per-lane straight from prepacked Wp (L2-resident, exact MFMA layout).
// Writes: Pout = bf16(A@Wn); out = (1-al)*(A@Wres+bias); EL/ER head-dots (heads 2w, 2w+1).
__global__ __launch_bounds__(256, 2) void gemm_k(const float* __restrict__ A,
                                              const u16* __restrict__ Wpn, const u16* __restrict__ Wpr,
                                              const float* __restrict__ bias,
                                              const float* __restrict__ alpha_ws, int tix,
                                              u16* __restrict__ Pout, float* __restrict__ out,
                                              const float* __restrict__ attnL, const float* __restrict__ attnR,
                                              float* __restrict__ ELb, float* __restrict__ ERb){
  const int tid = threadIdx.x;
  const int lane = tid & 63, wave = tid >> 6;
  const int quad = lane >> 4, n0 = lane & 15;
  const int wrow = blockIdx.x*64;            // rows owned by block
  const int cbase = wave*64;                 // cols owned by wave
  f32x4 accn[4][4], accr[4][4];              // [row frag f][col frag nt]
#pragma unroll
  for (int f = 0; f < 4; ++f)
#pragma unroll
    for (int nt = 0; nt < 4; ++nt){
      accn[f][nt] = f32x4{0.f,0.f,0.f,0.f};
      accr[f][nt] = f32x4{0.f,0.f,0.f,0.f};
    }

  for (int kt = 0; kt < 8; ++kt){
    // B fragments: 16B contiguous per lane, L2-hot
    const u16* bpn = Wpn + kt*8192 + (cbase + n0)*32 + quad*8;
    const u16* bpr = Wpr + kt*8192 + (cbase + n0)*32 + quad*8;
    bf16x8 bn[4], br[4];
#pragma unroll
    for (int nt = 0; nt < 4; ++nt){
      bn[nt] = *(const bf16x8*)(bpn + nt*16*32);
      br[nt] = *(const bf16x8*)(bpr + nt*16*32);
    }
    // A fragments: 4 row-groups of 16, fp32 -> bf16
    union { bf16x8 v; u16 s[8]; } af[4];
#pragma unroll
    for (int f = 0; f < 4; ++f){
      int row = wrow + f*16 + n0;
      if (row < N_NODES){
        const float* ap = A + (size_t)row*256 + kt*32 + quad*8;
        f32x4 a0 = *(const f32x4*)ap;
        f32x4 a1 = *(const f32x4*)(ap + 4);
#pragma unroll
        for (int j = 0; j < 4; ++j){ af[f].s[j] = f2bf(a0[j]); af[f].s[4+j] = f2bf(a1[j]); }
      } else {
#pragma unroll
        for (int j = 0; j < 8; ++j) af[f].s[j] = 0;
      }
    }
#pragma unroll
    for (int f = 0; f < 4; ++f)
#pragma unroll
      for (int nt = 0; nt < 4; ++nt){
        accn[f][nt] = __builtin_amdgcn_mfma_f32_16x16x32_bf16(af[f].v, bn[nt], accn[f][nt], 0, 0, 0);
        accr[f][nt] = __builtin_amdgcn_mfma_f32_16x16x32_bf16(af[f].v, br[nt], accr[f][nt], 0, 0, 0);
      }
  }

  const float one_m_al = 1.f - alpha_ws[tix];
#pragma unroll
  for (int f = 0; f < 4; ++f)
#pragma unroll
    for (int nt = 0; nt < 4; ++nt){
      int col = cbase + nt*16 + n0;
      float b = bias[col];
#pragma unroll
      for (int reg = 0; reg < 4; ++reg){
        int row = wrow + f*16 + quad*4 + reg;
        if (row < N_NODES){
          out[(size_t)row*256 + col] = one_m_al * (accr[f][nt][reg] + b);
          Pout[(size_t)row*256 + col] = f2bf(accn[f][nt][reg]);
        }
      }
    }

  // ---- fused EL/ER: wave covers heads h0=2*wave (nt 0,1) and h1=2*wave+1 (nt 2,3) ----
  const int h0 = 2*wave, h1 = 2*wave + 1;
  const float aL00 = attnL[h0*64 + n0], aL01 = attnL[h0*64 + 16 + n0];
  const float aL10 = attnL[h1*64 + n0], aL11 = attnL[h1*64 + 16 + n0];
  const float aR00 = attnR[h0*64 + n0], aR01 = attnR[h0*64 + 16 + n0];
  const float aR10 = attnR[h1*64 + n0], aR11 = attnR[h1*64 + 16 + n0];
#pragma unroll
  for (int f = 0; f < 4; ++f){
#pragma unroll
    for (int reg = 0; reg < 4; ++reg){
      float e0 = accn[f][0][reg]*aL00 + accn[f][1][reg]*aL01;
      float e1 = accn[f][2][reg]*aL10 + accn[f][3][reg]*aL11;
      float r0 = accn[f][0][reg]*aR00 + accn[f][1][reg]*aR01;
      float r1 = accn[f][2][reg]*aR10 + accn[f][3][reg]*aR11;
      e0 += __shfl_xor(e0, 1); e0 += __shfl_xor(e0, 2); e0 += __shfl_xor(e0, 4); e0 += __shfl_xor(e0, 8);
      e1 += __shfl_xor(e1, 1); e1 += __shfl_xor(e1, 2); e1 += __shfl_xor(e1, 4); e1 += __shfl_xor(e1, 8);
      r0 += __shfl_xor(r0, 1); r0 += __shfl_xor(r0, 2); r0 += __shfl_xor(r0, 4); r0 += __shfl_xor(r0, 8);
      r1 += __shfl_xor(r1, 1); r1 += __shfl_xor(r1, 2); r1 += __shfl_xor(r1, 4); r1 += __shfl_xor(r1, 8);
      int row = wrow + f*16 + quad*4 + reg;
      if (row < N_NODES){
        if (n0 == 0)      ELb[row*8 + h0] = e0;
        else if (n0 == 1) ELb[row*8 + h1] = e1;
        else if (n0 == 2) ERb[row*8 + h0] = r0;
        else if (n0 == 3) ERb[row*8 + h1] = r1;
      }
    }
  }
}

// ---------------- CSR build ----------------
__global__ void zero_k(int* __restrict__ p, int n){
  int i = blockIdx.x*256 + threadIdx.x; if (i < n) p[i] = 0;
}
__global__ void hist_k(const int* __restrict__ sr, const int* __restrict__ dr,
                       const int* __restrict__ sc, const int* __restrict__ dc,
                       int* __restrict__ counts){
  int r = blockIdx.y; int e = blockIdx.x*256 + threadIdx.x;
  if (e >= N_EDGES) return;
  const int* dst = (r == 0) ? dr : (r == 1) ? sr : (r == 2) ? dc : sc;
  atomicAdd(&counts[r*N_NODES + dst[e]], 1);
}
__global__ void scan1_k(const int* __restrict__ counts, int* __restrict__ rowptr,
                        int* __restrict__ bsums){
  int r = blockIdx.y; int i = blockIdx.x*256 + threadIdx.x;
  int lane = threadIdx.x & 63, wave = threadIdx.x >> 6;
  int v = (i < N_NODES) ? counts[r*N_NODES + i] : 0;
  int orig = v;
  for (int off = 1; off < 64; off <<= 1){ int t = __shfl_up(v, off); if (lane >= off) v += t; }
  __shared__ int wsum[4];
  if (lane == 63) wsum[wave] = v;
  __syncthreads();
  int add = 0;
  for (int w = 0; w < wave; ++w) add += wsum[w];
  v += add;
  if (i < N_NODES) rowptr[r*(N_NODES+1) + i] = v - orig;   // exclusive within block
  if (threadIdx.x == 255) bsums[r*196 + blockIdx.x] = v;
}
__global__ void scan2_k(int* __restrict__ bsums){   // 1 block; wave r scans its 196 sums
  int lane = threadIdx.x & 63, r = threadIdx.x >> 6;
  int carry = 0;
  for (int c = 0; c < 4; ++c){
    int i = c*64 + lane;
    int v = (i < 196) ? bsums[r*196 + i] : 0;
    int orig = v;
    for (int off = 1; off < 64; off <<= 1){ int t = __shfl_up(v, off); if (lane >= off) v += t; }
    int excl = v - orig + carry;
    if (i < 196) bsums[r*196 + i] = excl;
    carry += __shfl(v, 63);
  }
}
__global__ void scan3_k(const int* __restrict__ bsums, int* __restrict__ rowptr){
  int r = blockIdx.y; int i = blockIdx.x*256 + threadIdx.x;
  if (i < N_NODES) rowptr[r*(N_NODES+1) + i] += bsums[r*196 + blockIdx.x];
  if (i == N_NODES) rowptr[r*(N_NODES+1) + N_NODES] = N_EDGES;
}
__global__ void scatter_k(const int* __restrict__ sr, const int* __restrict__ dr,
                          const int* __restrict__ sc, const int* __restrict__ dc,
                          const int* __restrict__ rowptr, int* __restrict__ cur,
                          int* __restrict__ colsrc){
  int r = blockIdx.y; int e = blockIdx.x*256 + threadIdx.x;
  if (e >= N_EDGES) return;
  const int* dst = (r == 0) ? dr : (r == 1) ? sr : (r == 2) ? dc : sc;
  const int* src = (r == 0) ? sr : (r == 1) ? dr : (r == 2) ? sc : dc;
  int d = dst[e];
  int pos = rowptr[r*(N_NODES+1) + d] + atomicAdd(&cur[r*N_NODES + d], 1);
  colsrc[r*N_EDGES + pos] = src[e];
}

// ---------------- fused aggregate + residual blend + cross-relation attention ----------------
// one wave per (node, group g); handles relations {g, g+2} (same dtype -> same alpha).
// conv: single pass shift-softmax exp(x-10), 8-deep gather pipeline.
// blend: h = al*relu(conv) + inherit (inherit pre-scaled by (1-al), read from out).
// cross: 2-way softmax over the group in registers, final write to out.
__global__ __launch_bounds__(256) void aggcross_k(
    const int* __restrict__ rowptr, const int* __restrict__ colsrc,
    const float* __restrict__ EL, const float* __restrict__ ER,
    const u16* __restrict__ P, const float* __restrict__ rel_attn,
    const float* __restrict__ alpha_ws, float* __restrict__ out){
  const int g = blockIdx.y;                    // group base relation: {g, g+2}
  const int wave = threadIdx.x >> 6, lane = threadIdx.x & 63;
  const int n = blockIdx.x*4 + wave;
  if (n >= N_NODES) return;
  const int k0 = lane >> 3, j = lane & 7;
  const float al = alpha_ws[g ^ 1];            // DTYPE[g]: g=0 -> 1, g=1 -> 0
  f32x4 h[2];
#pragma unroll
  for (int which = 0; which < 2; ++which){
    const int r = g + which*2;
    const int rp0 = rowptr[r*(N_NODES+1) + n], rp1 = rowptr[r*(N_NODES+1) + n + 1];
    const float er = ER[(size_t)r*NE8 + n*8 + k0];
    const float* el = EL + (size_t)r*NE8;
    const int* cs = colsrc + r*N_EDGES;
    const u16* Ps = P + (size_t)(r ^ 1)*NP;

    float z = 0.f, a0 = 0.f, a1 = 0.f, a2 = 0.f, a3 = 0.f;
    for (int base = rp0; base < rp1; base += 8){
      const int cnt = rp1 - base;
      const int m = cnt < 8 ? cnt : 8;
      int sj = cs[base + (j < m ? j : 0)];
      float x = leaky(el[sj*8 + k0] + er);
      float p = (j < m) ? __expf(x - 10.f) : 0.f;
      ushort4 hv[8]; float pv[8];
#pragma unroll
      for (int t = 0; t < 8; ++t){
        if (t < m){
          int s = __shfl(sj, t);                                   // uniform broadcast
          hv[t] = *(const ushort4*)(Ps + (size_t)s*256 + lane*4);  // 512B coalesced row
          pv[t] = __shfl(p, (lane & 56) | t);                      // p(edge t, head k0)
        }
      }
#pragma unroll
      for (int t = 0; t < 8; ++t){
        if (t < m){
          float q = pv[t];
          z += q;
          a0 += q*bf2f(hv[t].x); a1 += q*bf2f(hv[t].y);
          a2 += q*bf2f(hv[t].z); a3 += q*bf2f(hv[t].w);
        }
      }
    }
    float inv = (rp1 > rp0) ? 1.f / z : 0.f;
    f32x4 inh = *(const f32x4*)(out + (size_t)r*NP + (size_t)n*256 + lane*4);
    h[which][0] = al * fmaxf(a0*inv, 0.f) + inh[0];
    h[which][1] = al * fmaxf(a1*inv, 0.f) + inh[1];
    h[which][2] = al * fmaxf(a2*inv, 0.f) + inh[2];
    h[which][3] = al * fmaxf(a3*inv, 0.f) + inh[3];
  }
  // cross-relation attention over {h[0], h[1]}
#pragma unroll
  for (int which = 0; which < 2; ++which){
    int rr = g + which*2;
    const float* ra = rel_attn + rr*256 + k0*32 + j*4;
    float s0 = 0.f, s1 = 0.f;
#pragma unroll
    for (int jj = 0; jj < 4; ++jj){
      float a = ra[jj];
      s0 += a * h[0][jj]; s1 += a * h[1][jj];
    }
    s0 += __shfl_xor(s0, 1); s1 += __shfl_xor(s1, 1);
    s0 += __shfl_xor(s0, 2); s1 += __shfl_xor(s1, 2);
    s0 += __shfl_xor(s0, 4); s1 += __shfl_xor(s1, 4);
    float l0 = leaky(s0), l1 = leaky(s1);
    float mx = fmaxf(l0, l1);
    float e0 = __expf(l0 - mx), e1 = __expf(l1 - mx);
    float w0 = e0 / (e0 + e1), w1 = 1.f - w0;
    f32x4 o;
#pragma unroll
    for (int jj = 0; jj < 4; ++jj) o[jj] = w0*h[0][jj] + w1*h[1][jj];
    *(f32x4*)(out + ((size_t)rr*N_NODES + n)*256 + lane*4) = o;
  }
}

extern "C" void kernel_launch(void* const* d_in, const int* in_sizes, int n_in,
                              void* d_out, int out_size, void* d_ws, size_t ws_size,
                              hipStream_t stream) {
  (void)in_sizes; (void)n_in; (void)out_size; (void)ws_size;
  const float* feats      = (const float*)d_in[0];
  const float* rel_feats  = (const float*)d_in[1];
  const int*   src_rates  = (const int*)d_in[2];
  const int*   dst_rates  = (const int*)d_in[3];
  const int*   src_clicks = (const int*)d_in[4];
  const int*   dst_clicks = (const int*)d_in[5];
  const float* W_node     = (const float*)d_in[6];
  const float* Wr         = (const float*)d_in[7];
  const float* Wres       = (const float*)d_in[8];
  const float* bres       = (const float*)d_in[9];
  const float* resw       = (const float*)d_in[10];
  const float* rel_attn   = (const float*)d_in[11];
  const float* Wupd       = (const float*)d_in[12];
  const float* bupd       = (const float*)d_in[13];

  char* w = (char*)d_ws;
  u16*   Wp     = (u16*)(w + WP_OFF);
  float* attn   = (float*)(w + ATTN_OFF);
  float* alpha  = (float*)(w + ALPHA_OFF);
  u16*   P      = (u16*)(w + P_OFF);
  float* EL     = (float*)(w + EL_OFF);
  float* ER     = (float*)(w + ER_OFF);
  int*   counts = (int*)(w + CNT_OFF);
  int*   cur    = (int*)(w + CUR_OFF);
  int*   rowptr = (int*)(w + ROW_OFF);
  int*   bsums  = (int*)(w + BS_OFF);
  int*   colsrc = (int*)(w + COL_OFF);
  float* out    = (float*)d_out;

  static const int DT[4] = {1, 0, 1, 0};   // DTYPE per relation / feat index

  // zero counts + cursors (contiguous: 400000 ints)
  zero_k<<<1563, 256, 0, stream>>>(counts, 400000);
  small_k<<<4, 256, 0, stream>>>(rel_feats, Wr, Wupd, bupd, resw, attn, alpha,
                                 out + (size_t)4*NP);
  prepack_k<<<1024, 256, 0, stream>>>(W_node, Wres, Wp);

  hist_k<<<dim3(1172, 4), 256, 0, stream>>>(src_rates, dst_rates, src_clicks, dst_clicks, counts);
  scan1_k<<<dim3(196, 4), 256, 0, stream>>>(counts, rowptr, bsums);
  scan2_k<<<1, 256, 0, stream>>>(bsums);
  scan3_k<<<dim3(196, 4), 256, 0, stream>>>(bsums, rowptr);
  scatter_k<<<dim3(1172, 4), 256, 0, stream>>>(src_rates, dst_rates, src_clicks, dst_clicks,
                                               rowptr, cur, colsrc);

  // fused dual GEMM per relation: P[i]=bf16(feats@Wn), out[i]=(1-al)*(feats@Wres+b),
  // EL[i^1]/ER[i] from fp32 accumulators
  for (int i = 0; i < 4; ++i)
    gemm_k<<<782, 256, 0, stream>>>(feats + (size_t)i*NP,
                                    Wp + DT[i]*65536, Wp + (2 + DT[i])*65536,
                                    bres + DT[i]*256, alpha, DT[i],
                                    P + (size_t)i*NP, out + (size_t)i*NP,
                                    attn + (i ^ 1)*512, attn + i*512 + 32,
                                    EL + (size_t)(i ^ 1)*NE8, ER + (size_t)i*NE8);

  // fused aggregate + blend + cross: groups {0,2} and {1,3}
  aggcross_k<<<dim3(12500, 2), 256, 0, stream>>>(rowptr, colsrc, EL, ER, P,
                                                 rel_attn, alpha, out);
}